// Round 1
// baseline (534.951 us; speedup 1.0000x reference)
//
#include <hip/hip_runtime.h>
#include <hip/hip_bf16.h>
#include <math.h>

#define B 64
#define O 64
#define F 1024
#define RN 16
#define RD 256
#define DEPTH 2
#define M (B*O)

// ---------------- A reductions: A1[b,o,o2] = sum_r A, A2[b,o,r] = sum_o2 A ----
__global__ __launch_bounds__(256) void k_reduceA(const float* __restrict__ A,
                                                 float* __restrict__ A1,
                                                 float* __restrict__ A2) {
  __shared__ float row[O * RN];
  const int bo = blockIdx.x;            // b*O + o
  const int t = threadIdx.x;
  *reinterpret_cast<float4*>(&row[t * 4]) =
      *reinterpret_cast<const float4*>(&A[(size_t)bo * (O * RN) + t * 4]);
  __syncthreads();
  if (t < O) {
    float s = 0.f;
#pragma unroll
    for (int r = 0; r < RN; ++r) s += row[t * RN + r];
    A1[(size_t)bo * O + t] = s;
  } else if (t < O + RN) {
    const int r = t - O;
    float s = 0.f;
#pragma unroll
    for (int o2 = 0; o2 < O; ++o2) s += row[o2 * RN + r];
    A2[(size_t)bo * RN + r] = s;
  }
}

// ---------------- xr_r = R @ Wrel[i][F:] + brel[i]  -> [RN][F] ---------------
__global__ __launch_bounds__(256) void k_xrr(const float* __restrict__ R,
                                             const float* __restrict__ Wr,  // [RD][F]
                                             const float* __restrict__ br,  // [F]
                                             float* __restrict__ xrr) {     // [RN][F]
  const int r = blockIdx.x >> 2;
  const int n = ((blockIdx.x & 3) << 8) + threadIdx.x;
  float s = br[n];
  for (int k = 0; k < RD; ++k) s += R[r * RD + k] * Wr[(size_t)k * F + n];
  xrr[(size_t)r * F + n] = s;
}

// ---------------- C[M,N] = X[M,K] @ W[K,N] (+bias), fp32 tiled ---------------
#define BM 64
#define BN 64
#define BK 16
__global__ __launch_bounds__(256) void k_gemm(const float* __restrict__ X,
                                              const float* __restrict__ W,
                                              const float* __restrict__ bias,
                                              float* __restrict__ C,
                                              int Mdim, int Ndim, int Kdim) {
  __shared__ float Xs[BK][BM];   // transposed tile: [k][m]
  __shared__ float Ws[BK][BN];   // natural: [k][n]
  const int t = threadIdx.x;
  const int bm = blockIdx.x * BM;
  const int bn = blockIdx.y * BN;
  const int tx = t & 15;
  const int ty = t >> 4;
  const int xr = t >> 2;          // 0..63 row of X tile
  const int xk = (t & 3) << 2;    // 0,4,8,12 k-offset
  const int wr = t >> 4;          // 0..15 row of W tile
  const int wc = (t & 15) << 2;   // col offset

  float acc[4][4];
#pragma unroll
  for (int i = 0; i < 4; ++i)
#pragma unroll
    for (int j = 0; j < 4; ++j) acc[i][j] = 0.f;

  for (int k0 = 0; k0 < Kdim; k0 += BK) {
    const float4 va = *reinterpret_cast<const float4*>(&X[(size_t)(bm + xr) * Kdim + k0 + xk]);
    const float4 vb = *reinterpret_cast<const float4*>(&W[(size_t)(k0 + wr) * Ndim + bn + wc]);
    Xs[xk + 0][xr] = va.x; Xs[xk + 1][xr] = va.y; Xs[xk + 2][xr] = va.z; Xs[xk + 3][xr] = va.w;
    *reinterpret_cast<float4*>(&Ws[wr][wc]) = vb;
    __syncthreads();
#pragma unroll
    for (int k = 0; k < BK; ++k) {
      const float4 a = *reinterpret_cast<const float4*>(&Xs[k][ty * 4]);
      const float4 b = *reinterpret_cast<const float4*>(&Ws[k][tx * 4]);
      acc[0][0] += a.x * b.x; acc[0][1] += a.x * b.y; acc[0][2] += a.x * b.z; acc[0][3] += a.x * b.w;
      acc[1][0] += a.y * b.x; acc[1][1] += a.y * b.y; acc[1][2] += a.y * b.z; acc[1][3] += a.y * b.w;
      acc[2][0] += a.z * b.x; acc[2][1] += a.z * b.y; acc[2][2] += a.z * b.z; acc[2][3] += a.z * b.w;
      acc[3][0] += a.w * b.x; acc[3][1] += a.w * b.y; acc[3][2] += a.w * b.z; acc[3][3] += a.w * b.w;
    }
    __syncthreads();
  }
  float4 bv = make_float4(0.f, 0.f, 0.f, 0.f);
  if (bias) bv = *reinterpret_cast<const float4*>(&bias[bn + tx * 4]);
#pragma unroll
  for (int i = 0; i < 4; ++i) {
    float4 o;
    o.x = acc[i][0] + bv.x; o.y = acc[i][1] + bv.y;
    o.z = acc[i][2] + bv.z; o.w = acc[i][3] + bv.w;
    *reinterpret_cast<float4*>(&C[(size_t)(bm + ty * 4 + i) * Ndim + bn + tx * 4]) = o;
  }
}

// ------- out = tanh(xs + A1[b]@xr_x[b] + A2[b]@xr_r + x_in), per (b, f-tile) -
__global__ __launch_bounds__(256) void k_agg(const float* __restrict__ A1,
                                             const float* __restrict__ A2,
                                             const float* __restrict__ xrx,
                                             const float* __restrict__ xrr,
                                             const float* __restrict__ xs,
                                             const float* __restrict__ xin,
                                             float* __restrict__ xout) {
  __shared__ float A1s[O][O + 1];
  __shared__ float A2s[O][RN + 1];
  __shared__ float Xls[O][132];
  __shared__ float Rls[RN][132];
  const int b = blockIdx.x;
  const int f0 = blockIdx.y * 128;
  const int t = threadIdx.x;

#pragma unroll
  for (int i = 0; i < 4; ++i) {
    const int gi = i * 1024 + t * 4;
    const float4 v = *reinterpret_cast<const float4*>(&A1[(size_t)b * O * O + gi]);
    const int o = gi >> 6, c = gi & 63;
    A1s[o][c] = v.x; A1s[o][c + 1] = v.y; A1s[o][c + 2] = v.z; A1s[o][c + 3] = v.w;
  }
  {
    const int gi = t * 4;
    const float4 v = *reinterpret_cast<const float4*>(&A2[(size_t)b * O * RN + gi]);
    const int o = gi >> 4, c = gi & 15;
    A2s[o][c] = v.x; A2s[o][c + 1] = v.y; A2s[o][c + 2] = v.z; A2s[o][c + 3] = v.w;
  }
#pragma unroll
  for (int i = 0; i < 8; ++i) {
    const int gi = i * 1024 + t * 4;
    const int o2 = gi >> 7, c = gi & 127;
    const float4 v = *reinterpret_cast<const float4*>(&xrx[((size_t)(b * O + o2)) * F + f0 + c]);
    Xls[o2][c] = v.x; Xls[o2][c + 1] = v.y; Xls[o2][c + 2] = v.z; Xls[o2][c + 3] = v.w;
  }
#pragma unroll
  for (int i = 0; i < 2; ++i) {
    const int gi = i * 1024 + t * 4;
    const int r = gi >> 7, c = gi & 127;
    const float4 v = *reinterpret_cast<const float4*>(&xrr[(size_t)r * F + f0 + c]);
    Rls[r][c] = v.x; Rls[r][c + 1] = v.y; Rls[r][c + 2] = v.z; Rls[r][c + 3] = v.w;
  }
  __syncthreads();

  const int ob = (t >> 4) << 2;   // 4 output rows per thread
  const int fc = (t & 15) << 2;   // 4+4 cols per thread (at fc and fc+64)
  float acc[4][8];
#pragma unroll
  for (int i = 0; i < 4; ++i)
#pragma unroll
    for (int j = 0; j < 8; ++j) acc[i][j] = 0.f;

#pragma unroll 4
  for (int o2 = 0; o2 < O; ++o2) {
    const float4 xa = *reinterpret_cast<const float4*>(&Xls[o2][fc]);
    const float4 xb = *reinterpret_cast<const float4*>(&Xls[o2][fc + 64]);
#pragma unroll
    for (int io = 0; io < 4; ++io) {
      const float a = A1s[ob + io][o2];
      acc[io][0] += a * xa.x; acc[io][1] += a * xa.y; acc[io][2] += a * xa.z; acc[io][3] += a * xa.w;
      acc[io][4] += a * xb.x; acc[io][5] += a * xb.y; acc[io][6] += a * xb.z; acc[io][7] += a * xb.w;
    }
  }
#pragma unroll
  for (int r = 0; r < RN; ++r) {
    const float4 xa = *reinterpret_cast<const float4*>(&Rls[r][fc]);
    const float4 xb = *reinterpret_cast<const float4*>(&Rls[r][fc + 64]);
#pragma unroll
    for (int io = 0; io < 4; ++io) {
      const float a = A2s[ob + io][r];
      acc[io][0] += a * xa.x; acc[io][1] += a * xa.y; acc[io][2] += a * xa.z; acc[io][3] += a * xa.w;
      acc[io][4] += a * xb.x; acc[io][5] += a * xb.y; acc[io][6] += a * xb.z; acc[io][7] += a * xb.w;
    }
  }

#pragma unroll
  for (int io = 0; io < 4; ++io) {
    const size_t base = ((size_t)(b * O + ob + io)) * F + f0;
#pragma unroll
    for (int seg = 0; seg < 2; ++seg) {
      const size_t idx = base + seg * 64 + fc;
      const float4 s = *reinterpret_cast<const float4*>(&xs[idx]);
      const float4 xi = *reinterpret_cast<const float4*>(&xin[idx]);
      float4 o;
      o.x = tanhf(acc[io][seg * 4 + 0] + s.x + xi.x);
      o.y = tanhf(acc[io][seg * 4 + 1] + s.y + xi.y);
      o.z = tanhf(acc[io][seg * 4 + 2] + s.z + xi.z);
      o.w = tanhf(acc[io][seg * 4 + 3] + s.w + xi.w);
      *reinterpret_cast<float4*>(&xout[idx]) = o;
    }
  }
}

extern "C" void kernel_launch(void* const* d_in, const int* in_sizes, int n_in,
                              void* d_out, int out_size, void* d_ws, size_t ws_size,
                              hipStream_t stream) {
  const float* x0    = (const float*)d_in[0];
  const float* A     = (const float*)d_in[1];
  const float* R     = (const float*)d_in[2];
  const float* Wself = (const float*)d_in[3];
  const float* bself = (const float*)d_in[4];
  const float* Wrel  = (const float*)d_in[5];
  const float* brel  = (const float*)d_in[6];
  float* out = (float*)d_out;

  float* ws  = (float*)d_ws;
  float* A1  = ws;                       // M*O      = 262144 floats
  float* A2  = A1 + (size_t)M * O;       // M*RN     = 65536
  float* xrr = A2 + (size_t)M * RN;      // RN*F     = 16384
  float* xs  = xrr + (size_t)RN * F;     // M*F      = 4194304
  float* xrx = xs + (size_t)M * F;       // M*F      = 4194304
  // total ws use: ~35 MB

  k_reduceA<<<M, 256, 0, stream>>>(A, A1, A2);

  for (int i = 0; i < DEPTH; ++i) {
    const float* X = (i == 0) ? x0 : out;           // layer 1 reads layer 0's output in d_out
    const float* Ws_i = Wself + (size_t)i * F * F;
    const float* Wr_i = Wrel + (size_t)i * (F + RD) * F;
    dim3 grid(M / BM, F / BN);
    k_gemm<<<grid, 256, 0, stream>>>(X, Ws_i, bself + (size_t)i * F, xs, M, F, F);
    k_gemm<<<grid, 256, 0, stream>>>(X, Wr_i, nullptr, xrx, M, F, F);
    k_xrr<<<RN * 4, 256, 0, stream>>>(R, Wr_i + (size_t)F * F, brel + (size_t)i * F, xrr);
    k_agg<<<dim3(B, F / 128), 256, 0, stream>>>(A1, A2, xrx, xrr, xs, X, out);
  }
}

// Round 2
// 218.040 us; speedup vs baseline: 2.4535x; 2.4535x over previous
//
#include <hip/hip_runtime.h>
#include <hip/hip_bf16.h>
#include <math.h>

#define B 64
#define O 64
#define F 1024
#define RN 16
#define RD 256
#define DEPTH 2
#define M (B*O)

typedef __attribute__((ext_vector_type(8))) short short8;
typedef __attribute__((ext_vector_type(4))) float f32x4;

// ---------- bf16 RNE helpers ----------
__device__ __forceinline__ unsigned short bf16_rne(float x) {
  unsigned u = __float_as_uint(x);
  unsigned r = (u + 0x7FFFu + ((u >> 16) & 1u)) >> 16;
  return (unsigned short)r;
}
__device__ __forceinline__ float bf16_f(unsigned short h) {
  return __uint_as_float(((unsigned)h) << 16);
}
__device__ __forceinline__ void split2(float x, unsigned short& h, unsigned short& l) {
  h = bf16_rne(x);
  l = bf16_rne(x - bf16_f(h));
}

__device__ __forceinline__ void gload_lds16(const unsigned short* g, void* l) {
  __builtin_amdgcn_global_load_lds(
      (const __attribute__((address_space(1))) unsigned int*)g,
      (__attribute__((address_space(3))) unsigned int*)l, 16, 0, 0);
}

// ---------------- A reductions: A1[b,o,o2] = sum_r A, A2[b,o,r] = sum_o2 A ----
__global__ __launch_bounds__(256) void k_reduceA(const float* __restrict__ A,
                                                 float* __restrict__ A1,
                                                 float* __restrict__ A2) {
  __shared__ float row[O * RN];
  const int bo = blockIdx.x;
  const int t = threadIdx.x;
  *reinterpret_cast<float4*>(&row[t * 4]) =
      *reinterpret_cast<const float4*>(&A[(size_t)bo * (O * RN) + t * 4]);
  __syncthreads();
  if (t < O) {
    float s = 0.f;
#pragma unroll
    for (int r = 0; r < RN; ++r) s += row[t * RN + r];
    A1[(size_t)bo * O + t] = s;
  } else if (t < O + RN) {
    const int r = t - O;
    float s = 0.f;
#pragma unroll
    for (int o2 = 0; o2 < O; ++o2) s += row[o2 * RN + r];
    A2[(size_t)bo * RN + r] = s;
  }
}

// ---------------- xr_r = R @ Wrel[i][F:] + brel[i]  -> [RN][F] ---------------
__global__ __launch_bounds__(256) void k_xrr(const float* __restrict__ R,
                                             const float* __restrict__ Wr,  // [RD][F]
                                             const float* __restrict__ br,
                                             float* __restrict__ xrr) {
  const int r = blockIdx.x >> 2;
  const int n = ((blockIdx.x & 3) << 8) + threadIdx.x;
  float s = br[n];
  for (int k = 0; k < RD; ++k) s += R[r * RD + k] * Wr[(size_t)k * F + n];
  xrr[(size_t)r * F + n] = s;
}

// ---------------- split X [4096][1024] f32 -> Xh, Xl bf16 (row-major) --------
__global__ __launch_bounds__(256) void k_splitX(const float* __restrict__ X,
                                                unsigned short* __restrict__ Xh,
                                                unsigned short* __restrict__ Xl) {
  const size_t i = ((size_t)blockIdx.x * 256 + threadIdx.x) * 4;
  const float4 v = *reinterpret_cast<const float4*>(&X[i]);
  unsigned short h0, h1, h2, h3, l0, l1, l2, l3;
  split2(v.x, h0, l0); split2(v.y, h1, l1); split2(v.z, h2, l2); split2(v.w, h3, l3);
  uint2 hp, lp;
  hp.x = (unsigned)h0 | ((unsigned)h1 << 16); hp.y = (unsigned)h2 | ((unsigned)h3 << 16);
  lp.x = (unsigned)l0 | ((unsigned)l1 << 16); lp.y = (unsigned)l2 | ((unsigned)l3 << 16);
  *reinterpret_cast<uint2*>(&Xh[i]) = hp;
  *reinterpret_cast<uint2*>(&Xl[i]) = lp;
}

// ------- split + transpose W [1024][1024] ([k][n]) -> Wht/Wlt rows [nOff+n][k]
__global__ __launch_bounds__(256) void k_splitW(const float* __restrict__ W,
                                                unsigned short* __restrict__ Wht,
                                                unsigned short* __restrict__ Wlt,
                                                int nOff) {
  __shared__ float T[32][33];
  const int k0 = blockIdx.x * 32, n0 = blockIdx.y * 32;
  const int t = threadIdx.x;
  const int r = t >> 3, c4 = (t & 7) << 2;
  const float4 v = *reinterpret_cast<const float4*>(&W[(size_t)(k0 + r) * 1024 + n0 + c4]);
  T[r][c4] = v.x; T[r][c4 + 1] = v.y; T[r][c4 + 2] = v.z; T[r][c4 + 3] = v.w;
  __syncthreads();
  unsigned short h[4], l[4];
#pragma unroll
  for (int j = 0; j < 4; ++j) split2(T[c4 + j][r], h[j], l[j]);
  uint2 hp, lp;
  hp.x = (unsigned)h[0] | ((unsigned)h[1] << 16); hp.y = (unsigned)h[2] | ((unsigned)h[3] << 16);
  lp.x = (unsigned)l[0] | ((unsigned)l[1] << 16); lp.y = (unsigned)l[2] | ((unsigned)l[3] << 16);
  const size_t o = (size_t)(nOff + n0 + r) * 1024 + k0 + c4;
  *reinterpret_cast<uint2*>(&Wht[o]) = hp;
  *reinterpret_cast<uint2*>(&Wlt[o]) = lp;
}

// ---------------- fused MFMA GEMM: C[M,2048] = [Xh|Xh|Xl] @ [Wh;Wl;Wh] -------
// 128x128 tile, 4 waves, BK=64, XOR-swizzled LDS, global_load_lds width 16.
__global__ __launch_bounds__(256) void k_gemm_mfma(
    const unsigned short* __restrict__ Xh, const unsigned short* __restrict__ Xl,
    const unsigned short* __restrict__ Wht, const unsigned short* __restrict__ Wlt,
    float* __restrict__ xs, float* __restrict__ xrx) {
  __shared__ __align__(16) char Al[128 * 128];  // 128 rows x 128B (64 bf16 k)
  __shared__ __align__(16) char Bl[128 * 128];
  const int t = threadIdx.x;
  const int lane = t & 63, w = t >> 6;
  int bid = blockIdx.x;
  bid = (bid & 7) * 64 + (bid >> 3);           // XCD swizzle (512 wgs, %8==0)
  const int bm = (bid & 31) * 128;
  const int bn = (bid >> 5) * 128;
  const int wr = w >> 1, wc = w & 1;

  f32x4 acc[4][4];
#pragma unroll
  for (int m = 0; m < 4; ++m)
#pragma unroll
    for (int n = 0; n < 4; ++n) acc[m][n] = (f32x4)0.f;

  const int srow = lane >> 3;            // + c*8
  const int sin = (lane & 7) << 4;       // dest byte within 128B row

  for (int kt = 0; kt < 48; ++kt) {      // 3072 / 64
    const int p = kt >> 4;               // K-piece: 0:Xh*Wh 1:Xh*Wl 2:Xl*Wh
    const int k0 = (kt & 15) << 6;       // element offset within [0,1024)
    const unsigned short* Asrc = (p < 2) ? Xh : Xl;
    const unsigned short* Bsrc = (p == 1) ? Wlt : Wht;
#pragma unroll
    for (int i = 0; i < 4; ++i) {
      const int c = (w << 2) + i;        // chunk 0..15, wave-uniform
      const int row = (c << 3) + srow;
      const int inrow = sin ^ ((row & 7) << 4);   // pre-swizzled SOURCE byte
      gload_lds16(Asrc + ((size_t)(bm + row) << 10) + k0 + (inrow >> 1), &Al[c << 10]);
      gload_lds16(Bsrc + ((size_t)(bn + row) << 10) + k0 + (inrow >> 1), &Bl[c << 10]);
    }
    __syncthreads();   // compiler drains vmcnt before barrier -> LDS valid

    const int ar = wr * 64 + (lane & 15);
    const int br = wc * 64 + (lane & 15);
    const int kbyte = (lane >> 4) << 4;
#pragma unroll
    for (int kk = 0; kk < 2; ++kk) {
      short8 a[4], b[4];
#pragma unroll
      for (int m = 0; m < 4; ++m) {
        const int row = ar + m * 16;
        const int off = (row << 7) + (((kk << 6) + kbyte) ^ ((row & 7) << 4));
        a[m] = *reinterpret_cast<const short8*>(&Al[off]);
      }
#pragma unroll
      for (int n = 0; n < 4; ++n) {
        const int row = br + n * 16;
        const int off = (row << 7) + (((kk << 6) + kbyte) ^ ((row & 7) << 4));
        b[n] = *reinterpret_cast<const short8*>(&Bl[off]);
      }
#pragma unroll
      for (int m = 0; m < 4; ++m)
#pragma unroll
        for (int n = 0; n < 4; ++n)
          acc[m][n] = __builtin_amdgcn_mfma_f32_16x16x32_bf16(a[m], b[n], acc[m][n], 0, 0, 0);
    }
    __syncthreads();
  }

  // epilogue: cols [0,1024) -> xs, [1024,2048) -> xrx (both [4096][1024])
  float* dst = (bn < 1024) ? xs : xrx;
  const int coff = bn & 1023;
  const int lrow = (lane >> 4) << 2;
  const int lcol = lane & 15;
#pragma unroll
  for (int m = 0; m < 4; ++m)
#pragma unroll
    for (int n = 0; n < 4; ++n) {
      const int gr = bm + wr * 64 + m * 16 + lrow;
      const int gc = coff + wc * 64 + n * 16 + lcol;
#pragma unroll
      for (int i = 0; i < 4; ++i)
        dst[((size_t)(gr + i) << 10) + gc] = acc[m][n][i];
    }
}

// ------- out = tanh(xs + bself + A1[b]@xr_x[b] + A2[b]@xr_r + x_in) ----------
__global__ __launch_bounds__(256) void k_agg(const float* __restrict__ A1,
                                             const float* __restrict__ A2,
                                             const float* __restrict__ xrx,
                                             const float* __restrict__ xrr,
                                             const float* __restrict__ xs,
                                             const float* __restrict__ bias,
                                             const float* __restrict__ xin,
                                             float* __restrict__ xout) {
  __shared__ float A1s[O][O + 1];
  __shared__ float A2s[O][RN + 1];
  __shared__ float Xls[O][132];
  __shared__ float Rls[RN][132];
  const int b = blockIdx.x;
  const int f0 = blockIdx.y * 128;
  const int t = threadIdx.x;

#pragma unroll
  for (int i = 0; i < 4; ++i) {
    const int gi = i * 1024 + t * 4;
    const float4 v = *reinterpret_cast<const float4*>(&A1[(size_t)b * O * O + gi]);
    const int o = gi >> 6, c = gi & 63;
    A1s[o][c] = v.x; A1s[o][c + 1] = v.y; A1s[o][c + 2] = v.z; A1s[o][c + 3] = v.w;
  }
  {
    const int gi = t * 4;
    const float4 v = *reinterpret_cast<const float4*>(&A2[(size_t)b * O * RN + gi]);
    const int o = gi >> 4, c = gi & 15;
    A2s[o][c] = v.x; A2s[o][c + 1] = v.y; A2s[o][c + 2] = v.z; A2s[o][c + 3] = v.w;
  }
#pragma unroll
  for (int i = 0; i < 8; ++i) {
    const int gi = i * 1024 + t * 4;
    const int o2 = gi >> 7, c = gi & 127;
    const float4 v = *reinterpret_cast<const float4*>(&xrx[((size_t)(b * O + o2)) * F + f0 + c]);
    Xls[o2][c] = v.x; Xls[o2][c + 1] = v.y; Xls[o2][c + 2] = v.z; Xls[o2][c + 3] = v.w;
  }
#pragma unroll
  for (int i = 0; i < 2; ++i) {
    const int gi = i * 1024 + t * 4;
    const int r = gi >> 7, c = gi & 127;
    const float4 v = *reinterpret_cast<const float4*>(&xrr[(size_t)r * F + f0 + c]);
    Rls[r][c] = v.x; Rls[r][c + 1] = v.y; Rls[r][c + 2] = v.z; Rls[r][c + 3] = v.w;
  }
  __syncthreads();

  const int ob = (t >> 4) << 2;
  const int fc = (t & 15) << 2;
  float acc[4][8];
#pragma unroll
  for (int i = 0; i < 4; ++i)
#pragma unroll
    for (int j = 0; j < 8; ++j) acc[i][j] = 0.f;

#pragma unroll 4
  for (int o2 = 0; o2 < O; ++o2) {
    const float4 xa = *reinterpret_cast<const float4*>(&Xls[o2][fc]);
    const float4 xb = *reinterpret_cast<const float4*>(&Xls[o2][fc + 64]);
#pragma unroll
    for (int io = 0; io < 4; ++io) {
      const float a = A1s[ob + io][o2];
      acc[io][0] += a * xa.x; acc[io][1] += a * xa.y; acc[io][2] += a * xa.z; acc[io][3] += a * xa.w;
      acc[io][4] += a * xb.x; acc[io][5] += a * xb.y; acc[io][6] += a * xb.z; acc[io][7] += a * xb.w;
    }
  }
#pragma unroll
  for (int r = 0; r < RN; ++r) {
    const float4 xa = *reinterpret_cast<const float4*>(&Rls[r][fc]);
    const float4 xb = *reinterpret_cast<const float4*>(&Rls[r][fc + 64]);
#pragma unroll
    for (int io = 0; io < 4; ++io) {
      const float a = A2s[ob + io][r];
      acc[io][0] += a * xa.x; acc[io][1] += a * xa.y; acc[io][2] += a * xa.z; acc[io][3] += a * xa.w;
      acc[io][4] += a * xb.x; acc[io][5] += a * xb.y; acc[io][6] += a * xb.z; acc[io][7] += a * xb.w;
    }
  }

#pragma unroll
  for (int io = 0; io < 4; ++io) {
    const size_t base = ((size_t)(b * O + ob + io)) * F + f0;
#pragma unroll
    for (int seg = 0; seg < 2; ++seg) {
      const size_t idx = base + seg * 64 + fc;
      const float4 s = *reinterpret_cast<const float4*>(&xs[idx]);
      const float4 bv = *reinterpret_cast<const float4*>(&bias[f0 + seg * 64 + fc]);
      const float4 xi = *reinterpret_cast<const float4*>(&xin[idx]);
      float4 o;
      o.x = tanhf(acc[io][seg * 4 + 0] + s.x + bv.x + xi.x);
      o.y = tanhf(acc[io][seg * 4 + 1] + s.y + bv.y + xi.y);
      o.z = tanhf(acc[io][seg * 4 + 2] + s.z + bv.z + xi.z);
      o.w = tanhf(acc[io][seg * 4 + 3] + s.w + bv.w + xi.w);
      *reinterpret_cast<float4*>(&xout[idx]) = o;
    }
  }
}

extern "C" void kernel_launch(void* const* d_in, const int* in_sizes, int n_in,
                              void* d_out, int out_size, void* d_ws, size_t ws_size,
                              hipStream_t stream) {
  const float* x0    = (const float*)d_in[0];
  const float* A     = (const float*)d_in[1];
  const float* R     = (const float*)d_in[2];
  const float* Wself = (const float*)d_in[3];
  const float* bself = (const float*)d_in[4];
  const float* Wrel  = (const float*)d_in[5];
  const float* brel  = (const float*)d_in[6];
  float* out = (float*)d_out;

  float* ws  = (float*)d_ws;
  float* A1  = ws;                          // 262144 f32
  float* A2  = A1 + (size_t)M * O;          // 65536
  float* xrr = A2 + (size_t)M * RN;         // 16384
  float* xs  = xrr + (size_t)RN * F;        // 4194304 (16MB)
  float* xrx = xs + (size_t)M * F;          // 4194304 (16MB)
  unsigned short* Xh  = (unsigned short*)(xrx + (size_t)M * F);  // 8MB
  unsigned short* Xl  = Xh + (size_t)M * F;                      // 8MB
  unsigned short* Wht = Xl + (size_t)M * F;                      // 4MB (2048x1024)
  unsigned short* Wlt = Wht + (size_t)2048 * 1024;               // 4MB
  // total ws use ~60MB

  k_reduceA<<<M, 256, 0, stream>>>(A, A1, A2);

  for (int i = 0; i < DEPTH; ++i) {
    const float* X = (i == 0) ? x0 : out;
    const float* Ws_i = Wself + (size_t)i * F * F;
    const float* Wr_i = Wrel + (size_t)i * (F + RD) * F;

    k_splitX<<<4096, 256, 0, stream>>>(X, Xh, Xl);
    k_splitW<<<dim3(32, 32), 256, 0, stream>>>(Ws_i, Wht, Wlt, 0);
    k_splitW<<<dim3(32, 32), 256, 0, stream>>>(Wr_i, Wht, Wlt, 1024);
    k_gemm_mfma<<<512, 256, 0, stream>>>(Xh, Xl, Wht, Wlt, xs, xrx);
    k_xrr<<<RN * 4, 256, 0, stream>>>(R, Wr_i + (size_t)F * F, brel + (size_t)i * F, xrr);
    k_agg<<<dim3(B, F / 128), 256, 0, stream>>>(A1, A2, xrx, xrr, xs,
                                                bself + (size_t)i * F, X, out);
  }
}

// Round 4
// 212.626 us; speedup vs baseline: 2.5159x; 1.0255x over previous
//
#include <hip/hip_runtime.h>
#include <hip/hip_bf16.h>
#include <math.h>

#define B 64
#define O 64
#define F 1024
#define RN 16
#define RD 256
#define DEPTH 2
#define M (B*O)

typedef __attribute__((ext_vector_type(8))) short short8;
typedef __attribute__((ext_vector_type(8))) _Float16 half8;
typedef __attribute__((ext_vector_type(4))) float f32x4;

#define RES_SCALE 2048.0f          // 2^11
#define RES_INV  (1.0f/2048.0f)

// ---------- fp16 split helpers: x = h + l*2^-11 (l stored pre-scaled) ----------
__device__ __forceinline__ unsigned short h2u(_Float16 h) {
  union { _Float16 h; unsigned short u; } c; c.h = h; return c.u;
}
__device__ __forceinline__ void split2(float x, unsigned short& h, unsigned short& l) {
  _Float16 hh = (_Float16)x;                       // RNE
  _Float16 ll = (_Float16)((x - (float)hh) * RES_SCALE);
  h = h2u(hh); l = h2u(ll);
}

__device__ __forceinline__ void gload_lds16(const unsigned short* g, void* l) {
  __builtin_amdgcn_global_load_lds(
      (const __attribute__((address_space(1))) unsigned int*)g,
      (__attribute__((address_space(3))) unsigned int*)l, 16, 0, 0);
}

// ---------------- A reductions: A1[b,o,o2] = sum_r A, A2[b,o,r] = sum_o2 A ----
__global__ __launch_bounds__(256) void k_reduceA(const float* __restrict__ A,
                                                 float* __restrict__ A1,
                                                 float* __restrict__ A2) {
  __shared__ float row[O * RN];
  const int bo = blockIdx.x;
  const int t = threadIdx.x;
  *reinterpret_cast<float4*>(&row[t * 4]) =
      *reinterpret_cast<const float4*>(&A[(size_t)bo * (O * RN) + t * 4]);
  __syncthreads();
  if (t < O) {
    float s = 0.f;
#pragma unroll
    for (int r = 0; r < RN; ++r) s += row[t * RN + r];
    A1[(size_t)bo * O + t] = s;
  } else if (t < O + RN) {
    const int r = t - O;
    float s = 0.f;
#pragma unroll
    for (int o2 = 0; o2 < O; ++o2) s += row[o2 * RN + r];
    A2[(size_t)bo * RN + r] = s;
  }
}

// ---------------- xr_r = R @ Wrel[i][F:] + brel[i]  -> [RN][F] ---------------
__global__ __launch_bounds__(256) void k_xrr(const float* __restrict__ R,
                                             const float* __restrict__ Wr,  // [RD][F]
                                             const float* __restrict__ br,
                                             float* __restrict__ xrr) {
  const int r = blockIdx.x >> 2;
  const int n = ((blockIdx.x & 3) << 8) + threadIdx.x;
  float s = br[n];
  for (int k = 0; k < RD; ++k) s += R[r * RD + k] * Wr[(size_t)k * F + n];
  xrr[(size_t)r * F + n] = s;
}

// ---------------- split X [4096][1024] f32 -> Xh, Xl fp16 (row-major) --------
__global__ __launch_bounds__(256) void k_splitX(const float* __restrict__ X,
                                                unsigned short* __restrict__ Xh,
                                                unsigned short* __restrict__ Xl) {
  const size_t i = ((size_t)blockIdx.x * 256 + threadIdx.x) * 4;
  const float4 v = *reinterpret_cast<const float4*>(&X[i]);
  unsigned short h0, h1, h2, h3, l0, l1, l2, l3;
  split2(v.x, h0, l0); split2(v.y, h1, l1); split2(v.z, h2, l2); split2(v.w, h3, l3);
  uint2 hp, lp;
  hp.x = (unsigned)h0 | ((unsigned)h1 << 16); hp.y = (unsigned)h2 | ((unsigned)h3 << 16);
  lp.x = (unsigned)l0 | ((unsigned)l1 << 16); lp.y = (unsigned)l2 | ((unsigned)l3 << 16);
  *reinterpret_cast<uint2*>(&Xh[i]) = hp;
  *reinterpret_cast<uint2*>(&Xl[i]) = lp;
}

// ------- split + transpose W [1024][1024] ([k][n]) -> Wht/Wlt rows [nOff+n][k]
__global__ __launch_bounds__(256) void k_splitW(const float* __restrict__ W,
                                                unsigned short* __restrict__ Wht,
                                                unsigned short* __restrict__ Wlt,
                                                int nOff) {
  __shared__ float T[32][33];
  const int k0 = blockIdx.x * 32, n0 = blockIdx.y * 32;
  const int t = threadIdx.x;
  const int r = t >> 3, c4 = (t & 7) << 2;
  const float4 v = *reinterpret_cast<const float4*>(&W[(size_t)(k0 + r) * 1024 + n0 + c4]);
  T[r][c4] = v.x; T[r][c4 + 1] = v.y; T[r][c4 + 2] = v.z; T[r][c4 + 3] = v.w;
  __syncthreads();
  unsigned short h[4], l[4];
#pragma unroll
  for (int j = 0; j < 4; ++j) split2(T[c4 + j][r], h[j], l[j]);
  uint2 hp, lp;
  hp.x = (unsigned)h[0] | ((unsigned)h[1] << 16); hp.y = (unsigned)h[2] | ((unsigned)h[3] << 16);
  lp.x = (unsigned)l[0] | ((unsigned)l[1] << 16); lp.y = (unsigned)l[2] | ((unsigned)l[3] << 16);
  const size_t o = (size_t)(nOff + n0 + r) * 1024 + k0 + c4;
  *reinterpret_cast<uint2*>(&Wht[o]) = hp;
  *reinterpret_cast<uint2*>(&Wlt[o]) = lp;
}

// ---------------- staging + compute helpers for the MFMA GEMM ----------------
__device__ __forceinline__ void stage_tiles(const unsigned short* __restrict__ Asrc,
                                            const unsigned short* __restrict__ Bsrc,
                                            int bm, int bn, int k0,
                                            int w, int srow, int sin,
                                            char* Al, char* Bl) {
#pragma unroll
  for (int i = 0; i < 4; ++i) {
    const int c = (w << 2) + i;          // chunk 0..15, wave-uniform
    const int row = (c << 3) + srow;
    const int inrow = sin ^ ((row & 7) << 4);   // pre-swizzled SOURCE byte
    gload_lds16(Asrc + ((size_t)(bm + row) << 10) + k0 + (inrow >> 1), Al + (c << 10));
    gload_lds16(Bsrc + ((size_t)(bn + row) << 10) + k0 + (inrow >> 1), Bl + (c << 10));
  }
}

__device__ __forceinline__ void compute_tile(const char* Al, const char* Bl,
                                             int ar, int br, int kbyte,
                                             f32x4 (&acc)[4][4]) {
#pragma unroll
  for (int kk = 0; kk < 2; ++kk) {
    half8 a[4], b[4];
#pragma unroll
    for (int m = 0; m < 4; ++m) {
      const int row = ar + m * 16;
      const int off = (row << 7) + (((kk << 6) + kbyte) ^ ((row & 7) << 4));
      a[m] = *reinterpret_cast<const half8*>(&Al[off]);
    }
#pragma unroll
    for (int n = 0; n < 4; ++n) {
      const int row = br + n * 16;
      const int off = (row << 7) + (((kk << 6) + kbyte) ^ ((row & 7) << 4));
      b[n] = *reinterpret_cast<const half8*>(&Bl[off]);
    }
#pragma unroll
    for (int m = 0; m < 4; ++m)
#pragma unroll
      for (int n = 0; n < 4; ++n)
        acc[m][n] = __builtin_amdgcn_mfma_f32_16x16x32_f16(a[m], b[n], acc[m][n], 0, 0, 0);
  }
}

// ------- fused MFMA GEMM: C[M,2048] = Xh@Wh + 2^-11*(Xh@Wl_st + Xl_st@Wh) ----
__global__ __launch_bounds__(256) void k_gemm_mfma(
    const unsigned short* __restrict__ Xh, const unsigned short* __restrict__ Xl,
    const unsigned short* __restrict__ Wht, const unsigned short* __restrict__ Wlt,
    float* __restrict__ xs, float* __restrict__ xrx) {
  __shared__ __align__(16) char Al[128 * 128];  // 128 rows x 128B (64 fp16 k)
  __shared__ __align__(16) char Bl[128 * 128];
  const int t = threadIdx.x;
  const int lane = t & 63, w = t >> 6;
  int bid = blockIdx.x;
  bid = (bid & 7) * 64 + (bid >> 3);           // XCD swizzle (512 wgs, %8==0)
  const int bm = (bid & 31) * 128;
  const int bn = (bid >> 5) * 128;
  const int wr = w >> 1, wc = w & 1;

  f32x4 accM[4][4], accR[4][4];
#pragma unroll
  for (int m = 0; m < 4; ++m)
#pragma unroll
    for (int n = 0; n < 4; ++n) { accM[m][n] = (f32x4)0.f; accR[m][n] = (f32x4)0.f; }

  const int srow = lane >> 3;
  const int sin = (lane & 7) << 4;
  const int ar = wr * 64 + (lane & 15);
  const int br = wc * 64 + (lane & 15);
  const int kbyte = (lane >> 4) << 4;

  // piece 0: Xh * Wh -> accM   (K = 1024)
  for (int kt = 0; kt < 16; ++kt) {
    stage_tiles(Xh, Wht, bm, bn, kt << 6, w, srow, sin, Al, Bl);
    __syncthreads();
    compute_tile(Al, Bl, ar, br, kbyte, accM);
    __syncthreads();
  }
  // pieces 1,2: Xh * Wl_st, Xl_st * Wh -> accR   (K = 2048)
  for (int kt = 0; kt < 32; ++kt) {
    const unsigned short* As = (kt < 16) ? Xh : Xl;
    const unsigned short* Bs = (kt < 16) ? Wlt : Wht;
    stage_tiles(As, Bs, bm, bn, (kt & 15) << 6, w, srow, sin, Al, Bl);
    __syncthreads();
    compute_tile(Al, Bl, ar, br, kbyte, accR);
    __syncthreads();
  }

  // epilogue: cols [0,1024) -> xs, [1024,2048) -> xrx (both [4096][1024])
  float* dst = (bn < 1024) ? xs : xrx;
  const int coff = bn & 1023;
  const int lrow = (lane >> 4) << 2;
  const int lcol = lane & 15;
#pragma unroll
  for (int m = 0; m < 4; ++m)
#pragma unroll
    for (int n = 0; n < 4; ++n) {
      const int gr = bm + wr * 64 + m * 16 + lrow;
      const int gc = coff + wc * 64 + n * 16 + lcol;
#pragma unroll
      for (int i = 0; i < 4; ++i)
        dst[((size_t)(gr + i) << 10) + gc] = accM[m][n][i] + accR[m][n][i] * RES_INV;
    }
}

// ------- out = tanh(xs + bself + A1[b]@xr_x[b] + A2[b]@xr_r + x_in) ----------
// Optionally also emits the fp16 split of out (for the next layer's GEMM).
__global__ __launch_bounds__(256) void k_agg(const float* __restrict__ A1,
                                             const float* __restrict__ A2,
                                             const float* __restrict__ xrx,
                                             const float* __restrict__ xrr,
                                             const float* __restrict__ xs,
                                             const float* __restrict__ bias,
                                             const float* __restrict__ xin,
                                             float* __restrict__ xout,
                                             unsigned short* __restrict__ XhO,
                                             unsigned short* __restrict__ XlO) {
  __shared__ float A1s[O][O + 1];
  __shared__ float A2s[O][RN + 1];
  __shared__ float Xls[O][132];
  __shared__ float Rls[RN][132];
  const int b = blockIdx.x;
  const int f0 = blockIdx.y * 128;
  const int t = threadIdx.x;

#pragma unroll
  for (int i = 0; i < 4; ++i) {
    const int gi = i * 1024 + t * 4;
    const float4 v = *reinterpret_cast<const float4*>(&A1[(size_t)b * O * O + gi]);
    const int o = gi >> 6, c = gi & 63;
    A1s[o][c] = v.x; A1s[o][c + 1] = v.y; A1s[o][c + 2] = v.z; A1s[o][c + 3] = v.w;
  }
  {
    const int gi = t * 4;
    const float4 v = *reinterpret_cast<const float4*>(&A2[(size_t)b * O * RN + gi]);
    const int o = gi >> 4, c = gi & 15;
    A2s[o][c] = v.x; A2s[o][c + 1] = v.y; A2s[o][c + 2] = v.z; A2s[o][c + 3] = v.w;
  }
#pragma unroll
  for (int i = 0; i < 8; ++i) {
    const int gi = i * 1024 + t * 4;
    const int o2 = gi >> 7, c = gi & 127;
    const float4 v = *reinterpret_cast<const float4*>(&xrx[((size_t)(b * O + o2)) * F + f0 + c]);
    Xls[o2][c] = v.x; Xls[o2][c + 1] = v.y; Xls[o2][c + 2] = v.z; Xls[o2][c + 3] = v.w;
  }
#pragma unroll
  for (int i = 0; i < 2; ++i) {
    const int gi = i * 1024 + t * 4;
    const int r = gi >> 7, c = gi & 127;
    const float4 v = *reinterpret_cast<const float4*>(&xrr[(size_t)r * F + f0 + c]);
    Rls[r][c] = v.x; Rls[r][c + 1] = v.y; Rls[r][c + 2] = v.z; Rls[r][c + 3] = v.w;
  }
  __syncthreads();

  const int ob = (t >> 4) << 2;
  const int fc = (t & 15) << 2;
  float acc[4][8];
#pragma unroll
  for (int i = 0; i < 4; ++i)
#pragma unroll
    for (int j = 0; j < 8; ++j) acc[i][j] = 0.f;

#pragma unroll 4
  for (int o2 = 0; o2 < O; ++o2) {
    const float4 xa = *reinterpret_cast<const float4*>(&Xls[o2][fc]);
    const float4 xb = *reinterpret_cast<const float4*>(&Xls[o2][fc + 64]);
#pragma unroll
    for (int io = 0; io < 4; ++io) {
      const float a = A1s[ob + io][o2];
      acc[io][0] += a * xa.x; acc[io][1] += a * xa.y; acc[io][2] += a * xa.z; acc[io][3] += a * xa.w;
      acc[io][4] += a * xb.x; acc[io][5] += a * xb.y; acc[io][6] += a * xb.z; acc[io][7] += a * xb.w;
    }
  }
#pragma unroll
  for (int r = 0; r < RN; ++r) {
    const float4 xa = *reinterpret_cast<const float4*>(&Rls[r][fc]);
    const float4 xb = *reinterpret_cast<const float4*>(&Rls[r][fc + 64]);
#pragma unroll
    for (int io = 0; io < 4; ++io) {
      const float a = A2s[ob + io][r];
      acc[io][0] += a * xa.x; acc[io][1] += a * xa.y; acc[io][2] += a * xa.z; acc[io][3] += a * xa.w;
      acc[io][4] += a * xb.x; acc[io][5] += a * xb.y; acc[io][6] += a * xb.z; acc[io][7] += a * xb.w;
    }
  }

#pragma unroll
  for (int io = 0; io < 4; ++io) {
    const size_t base = ((size_t)(b * O + ob + io)) * F + f0;
#pragma unroll
    for (int seg = 0; seg < 2; ++seg) {
      const size_t idx = base + seg * 64 + fc;
      const float4 s = *reinterpret_cast<const float4*>(&xs[idx]);
      const float4 bv = *reinterpret_cast<const float4*>(&bias[f0 + seg * 64 + fc]);
      const float4 xi = *reinterpret_cast<const float4*>(&xin[idx]);
      float4 o;
      o.x = tanhf(acc[io][seg * 4 + 0] + s.x + bv.x + xi.x);
      o.y = tanhf(acc[io][seg * 4 + 1] + s.y + bv.y + xi.y);
      o.z = tanhf(acc[io][seg * 4 + 2] + s.z + bv.z + xi.z);
      o.w = tanhf(acc[io][seg * 4 + 3] + s.w + bv.w + xi.w);
      *reinterpret_cast<float4*>(&xout[idx]) = o;
      if (XhO) {
        unsigned short h0, h1, h2, h3, l0, l1, l2, l3;
        split2(o.x, h0, l0); split2(o.y, h1, l1); split2(o.z, h2, l2); split2(o.w, h3, l3);
        uint2 hp, lp;
        hp.x = (unsigned)h0 | ((unsigned)h1 << 16); hp.y = (unsigned)h2 | ((unsigned)h3 << 16);
        lp.x = (unsigned)l0 | ((unsigned)l1 << 16); lp.y = (unsigned)l2 | ((unsigned)l3 << 16);
        *reinterpret_cast<uint2*>(&XhO[idx]) = hp;
        *reinterpret_cast<uint2*>(&XlO[idx]) = lp;
      }
    }
  }
}

extern "C" void kernel_launch(void* const* d_in, const int* in_sizes, int n_in,
                              void* d_out, int out_size, void* d_ws, size_t ws_size,
                              hipStream_t stream) {
  const float* x0    = (const float*)d_in[0];
  const float* A     = (const float*)d_in[1];
  const float* R     = (const float*)d_in[2];
  const float* Wself = (const float*)d_in[3];
  const float* bself = (const float*)d_in[4];
  const float* Wrel  = (const float*)d_in[5];
  const float* brel  = (const float*)d_in[6];
  float* out = (float*)d_out;

  float* ws  = (float*)d_ws;
  float* A1  = ws;                          // 262144 f32
  float* A2  = A1 + (size_t)M * O;          // 65536
  float* xrr = A2 + (size_t)M * RN;         // 16384
  float* xs  = xrr + (size_t)RN * F;        // 4194304 (16MB)
  float* xrx = xs + (size_t)M * F;          // 4194304 (16MB)
  unsigned short* Xh  = (unsigned short*)(xrx + (size_t)M * F);  // 8MB
  unsigned short* Xl  = Xh + (size_t)M * F;                      // 8MB
  unsigned short* Wht = Xl + (size_t)M * F;                      // 4MB (2048x1024)
  unsigned short* Wlt = Wht + (size_t)2048 * 1024;               // 4MB
  // total ws use ~60MB

  k_reduceA<<<M, 256, 0, stream>>>(A, A1, A2);
  k_splitX<<<4096, 256, 0, stream>>>(x0, Xh, Xl);

  for (int i = 0; i < DEPTH; ++i) {
    const float* X = (i == 0) ? x0 : out;
    const float* Ws_i = Wself + (size_t)i * F * F;
    const float* Wr_i = Wrel + (size_t)i * (F + RD) * F;

    k_splitW<<<dim3(32, 32), 256, 0, stream>>>(Ws_i, Wht, Wlt, 0);
    k_splitW<<<dim3(32, 32), 256, 0, stream>>>(Wr_i, Wht, Wlt, 1024);
    k_gemm_mfma<<<512, 256, 0, stream>>>(Xh, Xl, Wht, Wlt, xs, xrx);
    k_xrr<<<RN * 4, 256, 0, stream>>>(R, Wr_i + (size_t)F * F, brel + (size_t)i * F, xrr);
    const bool emit = (i + 1 < DEPTH);
    k_agg<<<dim3(B, F / 128), 256, 0, stream>>>(A1, A2, xrx, xrr, xs,
                                                bself + (size_t)i * F, X, out,
                                                emit ? Xh : nullptr,
                                                emit ? Xl : nullptr);
  }
}